// Round 1
// 882.016 us; speedup vs baseline: 9.0623x; 9.0623x over previous
//
#include <hip/hip_runtime.h>

// Koopman operator: z' = z + DT*(z@A^T + ((z@Vf)*a)@Uf), 8 steps fused.
// Column-parallel, weight-register-stationary rewrite:
//   block = 512 threads = 8 waves, 64 rows/block.
//   Wave w owns output col-tiles {2w, 2w+1} (A^T + phase-2 + z master accum
//   for all 64 rows); waves 0..5 additionally own one rank-16 proj tile.
//   All weight MFMA fragments live in VGPRs for the whole kernel (loaded once
//   per block) -- no global loads inside the step loop. z and proj round-trip
//   through LDS for the C-layout -> A-frag transpose. 2 barriers/step.

typedef __bf16 bf16_t;
typedef __bf16 bf16x8 __attribute__((ext_vector_type(8)));
typedef float f32x4 __attribute__((ext_vector_type(4)));

#define DT_C   0.1f
#define BMAX_C 0.3f

#define ZP 264   // z_lds row pitch (elems); 528 B rows, 16B-aligned for b128
#define PP 104   // p_lds row pitch

#define WT1_ELEMS (352 * 256)
#define WT2_ELEMS (256 * 96)

// ---------------- dtype detector --------------------------------------------
__global__ void detect_dtype(const unsigned int* __restrict__ Abits,
                             int* __restrict__ flag) {
  if (threadIdx.x == 0 && blockIdx.x == 0) {
    int plausible = 0;
    for (int i = 0; i < 64; ++i) {
      unsigned int w = Abits[i];
      int e0 = (int)((w >> 7) & 0xFFu);
      int e1 = (int)((w >> 23) & 0xFFu);
      plausible += (e0 >= 100 && e0 <= 133);
      plausible += (e1 >= 100 && e1 <= 133);
    }
    *flag = (plausible >= 112) ? 1 : 0;  // 1 = bf16 storage, 0 = fp32
  }
}

// ---------------- prep: fold tanh clamp + DT into transposed bf16 weights ---
// Wt1[i][j], i<256:  DT * A[i][j]
// Wt1[256+c][j]:     BMAX * tanh(B_V[l][j][r]),  c = l*16+r
// Wt2[i][c]:         DT * BMAX * tanh(B_U[l][i][r])
template <typename T, int MODE>
__global__ __launch_bounds__(256) void prep_weights(
    const int* __restrict__ flag, const T* __restrict__ A,
    const T* __restrict__ BU, const T* __restrict__ BV,
    bf16_t* __restrict__ wt1, bf16_t* __restrict__ wt2) {
  if (*flag != MODE) return;
  int idx = blockIdx.x * 256 + threadIdx.x;
  if (idx < WT1_ELEMS) {
    int i = idx >> 8;          // 0..351
    int j = idx & 255;
    float v;
    if (i < 256) {
      v = DT_C * (float)A[i * 256 + j];
    } else {
      int c = i - 256, l = c >> 4, r = c & 15;
      v = BMAX_C * tanhf((float)BV[(l * 256 + j) * 16 + r]);
    }
    wt1[idx] = (bf16_t)v;
  } else {
    int k = idx - WT1_ELEMS;
    if (k < WT2_ELEMS) {
      int i = k / 96, c = k % 96;
      int l = c >> 4, r = c & 15;
      wt2[k] = (bf16_t)(DT_C * BMAX_C * tanhf((float)BU[(l * 256 + i) * 16 + r]));
    }
  }
}

// ---------------- fused 8-step propagation ----------------------------------
template <typename T, int MODE>
__global__ __launch_bounds__(512, 2) void koopman_kernel(
    const int* __restrict__ flag, const T* __restrict__ zg,
    const T* __restrict__ ag, const int* __restrict__ steps_p,
    const bf16_t* __restrict__ wt1, const bf16_t* __restrict__ wt2,
    T* __restrict__ outg) {
  if (*flag != MODE) return;

  __shared__ __align__(16) bf16_t z_lds[64 * ZP];
  __shared__ __align__(16) bf16_t p_lds[64 * PP];

  const int tid = threadIdx.x;
  const int wave = tid >> 6;       // 0..7
  const int lane = tid & 63;
  const int col = lane & 15;       // MFMA n / C-col
  const int quad = lane >> 4;      // MFMA lane quad
  const long long row0 = (long long)blockIdx.x * 64;
  const int ct0 = wave * 2;        // owned col-tiles: ct0, ct0+1

  // ---- weight fragments: register-resident for the whole kernel ----------
  bf16x8 w1f[3][8];   // [0]/[1]: A^T tiles ct0/ct0+1; [2]: proj tile (wave<6)
  bf16x8 w2f[2][3];
#pragma unroll
  for (int kk = 0; kk < 8; ++kk) {
    w1f[0][kk] = *(const bf16x8*)&wt1[(size_t)(ct0 * 16 + col) * 256 + kk * 32 + quad * 8];
    w1f[1][kk] = *(const bf16x8*)&wt1[(size_t)((ct0 + 1) * 16 + col) * 256 + kk * 32 + quad * 8];
  }
  if (wave < 6) {
#pragma unroll
    for (int kk = 0; kk < 8; ++kk)
      w1f[2][kk] = *(const bf16x8*)&wt1[(size_t)(256 + wave * 16 + col) * 256 + kk * 32 + quad * 8];
  }
#pragma unroll
  for (int kk = 0; kk < 3; ++kk) {
    w2f[0][kk] = *(const bf16x8*)&wt2[(size_t)(ct0 * 16 + col) * 96 + kk * 32 + quad * 8];
    w2f[1][kk] = *(const bf16x8*)&wt2[(size_t)((ct0 + 1) * 16 + col) * 96 + kk * 32 + quad * 8];
  }

  // ---- a-scales for this wave's proj tile (a is step-invariant) ----------
  float ascale[16];
  if (wave < 6) {
#pragma unroll
    for (int rg = 0; rg < 4; ++rg)
#pragma unroll
      for (int reg = 0; reg < 4; ++reg)
        ascale[rg * 4 + reg] =
            (float)ag[(row0 + rg * 16 + quad * 4 + reg) * 6 + wave];
  }

  // ---- z master: fp32 C-layout regs for owned col-tiles, all 64 rows -----
  f32x4 zacc[2][4];
#pragma unroll
  for (int t = 0; t < 2; ++t)
#pragma unroll
    for (int rg = 0; rg < 4; ++rg)
#pragma unroll
      for (int reg = 0; reg < 4; ++reg)
        zacc[t][rg][reg] =
            (float)zg[(row0 + rg * 16 + quad * 4 + reg) * 256 + (ct0 + t) * 16 + col];

  const int steps = steps_p[0];

  for (int s = 0; s < steps; ++s) {
    // scatter current z (bf16) into LDS; each wave writes its own col-tiles
#pragma unroll
    for (int t = 0; t < 2; ++t)
#pragma unroll
      for (int rg = 0; rg < 4; ++rg)
#pragma unroll
        for (int reg = 0; reg < 4; ++reg)
          z_lds[(rg * 16 + quad * 4 + reg) * ZP + (ct0 + t) * 16 + col] =
              (bf16_t)zacc[t][rg][reg];
    __syncthreads();

    // ---- phase 1: z @ Wt1 over all 4 row-groups (K=256) -------------------
#pragma unroll
    for (int rg = 0; rg < 4; ++rg) {
      bf16x8 zf[8];
#pragma unroll
      for (int kk = 0; kk < 8; ++kk)
        zf[kk] = *(const bf16x8*)&z_lds[(rg * 16 + col) * ZP + kk * 32 + quad * 8];
      f32x4 a0 = zacc[0][rg], a1 = zacc[1][rg];
      f32x4 pr = {0.f, 0.f, 0.f, 0.f};
      __builtin_amdgcn_s_setprio(1);
#pragma unroll
      for (int kk = 0; kk < 8; ++kk) {
        a0 = __builtin_amdgcn_mfma_f32_16x16x32_bf16(zf[kk], w1f[0][kk], a0, 0, 0, 0);
        a1 = __builtin_amdgcn_mfma_f32_16x16x32_bf16(zf[kk], w1f[1][kk], a1, 0, 0, 0);
      }
      if (wave < 6) {
#pragma unroll
        for (int kk = 0; kk < 8; ++kk)
          pr = __builtin_amdgcn_mfma_f32_16x16x32_bf16(zf[kk], w1f[2][kk], pr, 0, 0, 0);
      }
      __builtin_amdgcn_s_setprio(0);
      zacc[0][rg] = a0;
      zacc[1][rg] = a1;
      if (wave < 6) {
#pragma unroll
        for (int reg = 0; reg < 4; ++reg)
          p_lds[(rg * 16 + quad * 4 + reg) * PP + wave * 16 + col] =
              (bf16_t)(pr[reg] * ascale[rg * 4 + reg]);
      }
    }
    __syncthreads();

    // ---- phase 2: z += (proj*a) @ Wt2 (K=96) ------------------------------
#pragma unroll
    for (int rg = 0; rg < 4; ++rg) {
      bf16x8 pf[3];
#pragma unroll
      for (int kk = 0; kk < 3; ++kk)
        pf[kk] = *(const bf16x8*)&p_lds[(rg * 16 + col) * PP + kk * 32 + quad * 8];
      f32x4 a0 = zacc[0][rg], a1 = zacc[1][rg];
      __builtin_amdgcn_s_setprio(1);
#pragma unroll
      for (int kk = 0; kk < 3; ++kk) {
        a0 = __builtin_amdgcn_mfma_f32_16x16x32_bf16(pf[kk], w2f[0][kk], a0, 0, 0, 0);
        a1 = __builtin_amdgcn_mfma_f32_16x16x32_bf16(pf[kk], w2f[1][kk], a1, 0, 0, 0);
      }
      __builtin_amdgcn_s_setprio(0);
      zacc[0][rg] = a0;
      zacc[1][rg] = a1;
    }
    // no barrier needed here: next iter's z_lds writes are protected by the
    // post-scatter barrier; p_lds reads above complete before any wave can
    // pass that barrier and re-write p_lds in phase 1.
  }

  // ---- epilogue: direct C-layout stores in native dtype -------------------
#pragma unroll
  for (int t = 0; t < 2; ++t)
#pragma unroll
    for (int rg = 0; rg < 4; ++rg)
#pragma unroll
      for (int reg = 0; reg < 4; ++reg)
        outg[(row0 + rg * 16 + quad * 4 + reg) * 256 + (ct0 + t) * 16 + col] =
            (T)zacc[t][rg][reg];
}

extern "C" void kernel_launch(void* const* d_in, const int* in_sizes, int n_in,
                              void* d_out, int out_size, void* d_ws,
                              size_t ws_size, hipStream_t stream) {
  const void* z = d_in[0];
  const void* a = d_in[1];
  const void* A = d_in[2];
  const void* BU = d_in[3];
  const void* BV = d_in[4];
  const int* steps = (const int*)d_in[5];

  int* flag = (int*)d_ws;
  bf16_t* wt1 = (bf16_t*)((char*)d_ws + 16);
  bf16_t* wt2 = wt1 + WT1_ELEMS;

  const int N = in_sizes[0] / 256;  // 262144 rows

  detect_dtype<<<1, 64, 0, stream>>>((const unsigned int*)A, flag);

  // 352*256 + 256*96 = 114688 elements == 448 * 256 threads
  prep_weights<float, 0><<<448, 256, 0, stream>>>(
      flag, (const float*)A, (const float*)BU, (const float*)BV, wt1, wt2);
  prep_weights<bf16_t, 1><<<448, 256, 0, stream>>>(
      flag, (const bf16_t*)A, (const bf16_t*)BU, (const bf16_t*)BV, wt1, wt2);

  koopman_kernel<float, 0><<<N / 64, 512, 0, stream>>>(
      flag, (const float*)z, (const float*)a, steps, wt1, wt2, (float*)d_out);
  koopman_kernel<bf16_t, 1><<<N / 64, 512, 0, stream>>>(
      flag, (const bf16_t*)z, (const bf16_t*)a, steps, wt1, wt2,
      (bf16_t*)d_out);
}